// Round 7
// baseline (338.643 us; speedup 1.0000x reference)
//
#include <hip/hip_runtime.h>
#include <hip/hip_bf16.h>

#define NN 50000
#define NE 600000
#define DD 128
#define RR 8
#define KY 1152   /* Y cols: 8 relations * 128 + root 128 */

#define N2 (NN * RR)                       /* (v,r) segments, v-major */
#define SCHUNK 1024
#define NBS2 ((N2 + SCHUNK - 1) / SCHUNK)  /* 391 */
#define MGRID ((NN + 127) / 128)           /* 391 row-tiles */

typedef __attribute__((ext_vector_type(8))) short short8;
typedef __attribute__((ext_vector_type(4))) float f32x4;
typedef __attribute__((ext_vector_type(4))) unsigned uint4v;

__device__ __forceinline__ unsigned short f2b(float x){
  __hip_bfloat16 h = __float2bfloat16(x);
  return __builtin_bit_cast(unsigned short, h);
}
__device__ __forceinline__ float blo(unsigned u){ return __builtin_bit_cast(float, u << 16); }
__device__ __forceinline__ float bhi(unsigned u){ return __builtin_bit_cast(float, u & 0xFFFF0000u); }
__device__ __forceinline__ unsigned pack2(float a, float b){
  return (unsigned)f2b(a) | ((unsigned)f2b(b) << 16);
}

#define GLDS16(g, l) __builtin_amdgcn_global_load_lds( \
    (const __attribute__((address_space(1))) void*)(g), \
    (__attribute__((address_space(3))) void*)(l), 16, 0, 0)

// ---------------- edge structure build: CSR over v-major (dst, rel) segments ----------------
__global__ __launch_bounds__(256) void k_hist(const int* __restrict__ ei,
                                              const int* __restrict__ et,
                                              int* __restrict__ cnt) {
  int e = blockIdx.x * 256 + threadIdx.x;
  if (e < NE) {
    int dst = ei[NE + e];
    int r = et[e];
    atomicAdd(&cnt[dst * RR + r], 1);
  }
}

__global__ __launch_bounds__(256) void k_scan1(const int* __restrict__ cnt,
                                               int* __restrict__ bsum) {
  int b = blockIdx.x, t = threadIdx.x;
  int base = b * SCHUNK + t * 4;
  int s = 0;
  if (base < N2) {
    int4 v = *(const int4*)&cnt[base];
    s = v.x + v.y + v.z + v.w;
  }
  #pragma unroll
  for (int off = 32; off; off >>= 1) s += __shfl_down(s, off);
  __shared__ int wsum[4];
  int lane = t & 63, wv = t >> 6;
  if (lane == 0) wsum[wv] = s;
  __syncthreads();
  if (t == 0) bsum[b] = wsum[0] + wsum[1] + wsum[2] + wsum[3];
}

__global__ __launch_bounds__(512) void k_scan2(const int* __restrict__ bsum,
                                               int* __restrict__ boff) {
  int t = threadIdx.x, lane = t & 63, wv = t >> 6;
  int v = (t < NBS2) ? bsum[t] : 0;
  int x = v;
  #pragma unroll
  for (int off = 1; off < 64; off <<= 1) {
    int y = __shfl_up(x, off);
    if (lane >= off) x += y;
  }
  __shared__ int wt[8];
  if (lane == 63) wt[wv] = x;
  __syncthreads();
  int woff = 0;
  for (int w = 0; w < wv; w++) woff += wt[w];
  if (t < NBS2) boff[t] = woff + x - v;
}

__global__ __launch_bounds__(256) void k_scan3(const int* __restrict__ cnt,
                                               const int* __restrict__ boff,
                                               int* __restrict__ rp2,
                                               int* __restrict__ cur2) {
  int b = blockIdx.x, t = threadIdx.x;
  int lane = t & 63, wv = t >> 6;
  int base = b * SCHUNK + t * 4;
  int v[4] = {0, 0, 0, 0};
  int s = 0;
  if (base < N2) {
    int4 q = *(const int4*)&cnt[base];
    v[0] = q.x; v[1] = q.y; v[2] = q.z; v[3] = q.w;
    s = q.x + q.y + q.z + q.w;
  }
  int x = s;
  #pragma unroll
  for (int off = 1; off < 64; off <<= 1) {
    int y = __shfl_up(x, off);
    if (lane >= off) x += y;
  }
  __shared__ int wtot[4];
  if (lane == 63) wtot[wv] = x;
  __syncthreads();
  int woff = 0;
  for (int w = 0; w < wv; w++) woff += wtot[w];
  int exc = boff[b] + woff + x - s;
  if (base < N2) {
    #pragma unroll
    for (int j = 0; j < 4; j++) {
      cur2[base + j] = exc;
      rp2[base + j + 1] = exc + v[j];
      exc += v[j];
    }
  }
  if (b == 0 && t == 0) rp2[0] = 0;
}

__global__ __launch_bounds__(256) void k_scatter(const int* __restrict__ ei,
                                                 const int* __restrict__ et,
                                                 int* __restrict__ cur2,
                                                 unsigned* __restrict__ packed) {
  int e = blockIdx.x * 256 + threadIdx.x;
  if (e < NE) {
    int src = ei[e];
    int dst = ei[NE + e];
    int r = et[e];
    int p = atomicAdd(&cur2[dst * RR + r], 1);
    packed[p] = (unsigned)src | ((unsigned)r << 16);   // src < 65536
  }
}

// ---------------- prep: bf16 conversions ----------------
__global__ __launch_bounds__(256) void k_xb(const float* __restrict__ x,
                                            unsigned* __restrict__ xb2) {
  int i = blockIdx.x * 256 + threadIdx.x;
  if (i < NN * (DD / 2)) {
    float2 v = ((const float2*)x)[i];
    xb2[i] = pack2(v.x, v.y);
  }
}

// WT2[l][j][k] bf16, j in [0,1152): j<1024 -> rel_w[l][j>>7][k][j&127], else root_w[l][k][j-1024]
__global__ __launch_bounds__(256) void k_wt2(const float* __restrict__ rel_w,
                                             const float* __restrict__ root_w,
                                             unsigned short* __restrict__ WT2) {
  int idx = blockIdx.x * 256 + threadIdx.x;
  if (idx >= 2 * KY * DD) return;
  int k = idx % DD;
  int j = (idx / DD) % KY;
  int l = idx / (DD * KY);
  float v;
  if (j < RR * DD) v = rel_w[(((size_t)l * RR + (j >> 7)) * DD + k) * DD + (j & 127)];
  else             v = root_w[((size_t)l * DD + k) * DD + (j - RR * DD)];
  WT2[idx] = f2b(v);
}

// PT[n][k] = proj_w[k][n], k<256
__global__ __launch_bounds__(256) void k_pt(const float* __restrict__ proj_w,
                                            unsigned short* __restrict__ PT) {
  int idx = blockIdx.x * 256 + threadIdx.x;
  if (idx >= DD * 256) return;
  int k = idx % 256;
  int n = idx / 256;
  PT[idx] = f2b(proj_w[(size_t)k * DD + n]);
}

// ---------------- Y-GEMM v3: Y[M,1152] = A[M,128] @ W'[128,1152]  (bf16 out) ----------------
// No input staging: A (12.8MB) and B2 (0.29MB) are L2-resident; fragments read
// directly from global. LDS only for C restage (32KB). XCD-grouped work map:
// the 9 col-tiles of a row-tile run consecutively on the same XCD -> A-tile
// HBM-fetched once, L2-hit 8x.
__global__ __launch_bounds__(256) void k_ygemm(const unsigned short* __restrict__ A, int lda,
                                               const unsigned short* __restrict__ B2, /* [1152][128] */
                                               unsigned short* __restrict__ Y) {
  __shared__ unsigned short smC[128 * 128];   // 32 KB
  int t = threadIdx.x;
  // bijective XCD-grouped mapping (grid = MGRID*9 = 3519)
  const int nb = MGRID * 9, q8 = nb >> 3, r8 = nb & 7;   // 3519, 439, 7
  int xcd = blockIdx.x & 7, idx = blockIdx.x >> 3;
  int w = (xcd < r8 ? xcd * (q8 + 1) : r8 * (q8 + 1) + (xcd - r8) * q8) + idx;
  int rt = w / 9, ct = w % 9;

  int lane = t & 63, wv = t >> 6;
  int wm = wv >> 1, wn = wv & 1;
  int l15 = lane & 15, lk = lane >> 4;

  // per-lane fragment row addresses
  size_t aoff[4], boff4[4];
  #pragma unroll
  for (int q = 0; q < 4; q++) {
    int rg = rt * 128 + wm * 64 + q * 16 + l15; if (rg >= NN) rg = NN - 1;
    aoff[q] = (size_t)rg * lda;
    boff4[q] = (size_t)(ct * 128 + wn * 64 + q * 16 + l15) * DD;
  }

  f32x4 acc[4][4];
  #pragma unroll
  for (int mi = 0; mi < 4; mi++)
    #pragma unroll
    for (int ni = 0; ni < 4; ni++)
      acc[mi][ni] = (f32x4){0.f, 0.f, 0.f, 0.f};

  // register-double-buffered k-loop, fragments straight from L2
  short8 afA[4], bfA[4], afB[4], bfB[4];
  #pragma unroll
  for (int q = 0; q < 4; q++) {
    afA[q] = *(const short8*)(A + aoff[q] + lk * 8);
    bfA[q] = *(const short8*)(B2 + boff4[q] + lk * 8);
  }
  #pragma unroll
  for (int kk = 0; kk < 4; kk++) {
    if ((kk & 1) == 0) {
      if (kk < 3) {
        #pragma unroll
        for (int q = 0; q < 4; q++) {
          afB[q] = *(const short8*)(A + aoff[q] + ((kk + 1) * 4 + lk) * 8);
          bfB[q] = *(const short8*)(B2 + boff4[q] + ((kk + 1) * 4 + lk) * 8);
        }
      }
      #pragma unroll
      for (int mi = 0; mi < 4; mi++)
        #pragma unroll
        for (int ni = 0; ni < 4; ni++)
          acc[mi][ni] = __builtin_amdgcn_mfma_f32_16x16x32_bf16(afA[mi], bfA[ni], acc[mi][ni], 0, 0, 0);
    } else {
      if (kk < 3) {
        #pragma unroll
        for (int q = 0; q < 4; q++) {
          afA[q] = *(const short8*)(A + aoff[q] + ((kk + 1) * 4 + lk) * 8);
          bfA[q] = *(const short8*)(B2 + boff4[q] + ((kk + 1) * 4 + lk) * 8);
        }
      }
      #pragma unroll
      for (int mi = 0; mi < 4; mi++)
        #pragma unroll
        for (int ni = 0; ni < 4; ni++)
          acc[mi][ni] = __builtin_amdgcn_mfma_f32_16x16x32_bf16(afB[mi], bfB[ni], acc[mi][ni], 0, 0, 0);
    }
  }

  // restage C into smC, bf16, chunk-swizzled: col c of row r -> chunk (c>>3)^(r&7)
  #pragma unroll
  for (int mi = 0; mi < 4; mi++)
    #pragma unroll
    for (int ni = 0; ni < 4; ni++) {
      int col = wn * 64 + ni * 16 + l15;
      #pragma unroll
      for (int j = 0; j < 4; j++) {
        int row = wm * 64 + mi * 16 + lk * 4 + j;
        smC[row * 128 + ((((col >> 3) ^ (row & 7)) << 3) | (col & 7))] = f2b(acc[mi][ni][j]);
      }
    }
  __syncthreads();

  // write-out: thread t covers half a row (64 shorts = 128B) via 8x16B chunks
  {
    int row = t >> 1, half = t & 1;
    int rg = rt * 128 + row;
    if (rg < NN) {
      unsigned short* dst = Y + (size_t)rg * KY + ct * 128 + half * 64;
      #pragma unroll
      for (int i = 0; i < 8; i++) {
        int cc = half * 8 + i;
        ((uint4v*)dst)[i] = *(const uint4v*)&smC[row * 128 + ((cc ^ (row & 7)) << 3)];
      }
    }
  }
}

// ---------------- weighted gather: out[v] = sum_e w_e * Y[src_e, r_e*128:] + Y[v,1024:] + bias ----------------
__global__ __launch_bounds__(256) void k_aggD(const unsigned short* __restrict__ Y,
                                              const unsigned* __restrict__ packed,
                                              const int* __restrict__ rp2,
                                              const float* __restrict__ bias,
                                              float* __restrict__ outf,
                                              unsigned short* __restrict__ hb, int hboff) {
  int v = blockIdx.x * 4 + (threadIdx.x >> 6);
  int lane = threadIdx.x & 63;
  int q = lane >> 4, sub = lane & 15;

  // fenceposts rp2[v*8 .. v*8+8] on lanes 0..8
  int f = 0;
  if (lane <= 8) f = rp2[v * RR + lane];
  int fn = __shfl(f, lane + 1);             // lane l: rp2[v*8+l+1] (l<8 valid)
  int c = fn - f;
  float winv = (lane < 8 && c > 0) ? 1.f / (float)c : 0.f;
  int e0 = __shfl(f, 0), e1 = __shfl(f, 8);

  float acc[8];
  #pragma unroll
  for (int j = 0; j < 8; j++) acc[j] = 0.f;

  // 4 quarter-waves, each owns 16B of the row, 4 edges in flight
  for (int e = e0 + q; e < e1; e += 4) {
    unsigned rec = packed[e];
    int src = rec & 0xFFFF;
    int r = rec >> 16;
    float w = __shfl(winv, r);
    const uint4v* p = (const uint4v*)(Y + (size_t)src * KY + r * DD + sub * 8);
    uint4v u = *p;
    #pragma unroll
    for (int i = 0; i < 4; i++) {
      acc[2 * i]     += w * blo(u[i]);
      acc[2 * i + 1] += w * bhi(u[i]);
    }
  }

  // root term (once, quarter 0)
  if (q == 0) {
    uint4v u = *(const uint4v*)(Y + (size_t)v * KY + RR * DD + sub * 8);
    #pragma unroll
    for (int i = 0; i < 4; i++) {
      acc[2 * i]     += blo(u[i]);
      acc[2 * i + 1] += bhi(u[i]);
    }
  }

  // reduce across quarters
  #pragma unroll
  for (int j = 0; j < 8; j++) {
    acc[j] += __shfl_xor(acc[j], 32);
    acc[j] += __shfl_xor(acc[j], 16);
  }

  if (q == 0) {
    float4 b0 = *(const float4*)&bias[sub * 8];
    float4 b1 = *(const float4*)&bias[sub * 8 + 4];
    float val[8];
    val[0] = fmaxf(acc[0] + b0.x, 0.f); val[1] = fmaxf(acc[1] + b0.y, 0.f);
    val[2] = fmaxf(acc[2] + b0.z, 0.f); val[3] = fmaxf(acc[3] + b0.w, 0.f);
    val[4] = fmaxf(acc[4] + b1.x, 0.f); val[5] = fmaxf(acc[5] + b1.y, 0.f);
    val[6] = fmaxf(acc[6] + b1.z, 0.f); val[7] = fmaxf(acc[7] + b1.w, 0.f);
    float4* of = (float4*)&outf[(size_t)v * DD + sub * 8];
    of[0] = (float4){val[0], val[1], val[2], val[3]};
    of[1] = (float4){val[4], val[5], val[6], val[7]};
    uint4v hv;
    #pragma unroll
    for (int i = 0; i < 4; i++) hv[i] = pack2(val[2 * i], val[2 * i + 1]);
    *(uint4v*)(hb + (size_t)v * 256 + hboff + sub * 8) = hv;
  }
}

// ---------------- bf16 MFMA GEMM (projection): C[M,128] = A[M,K] * BT[128,K]^T + bias ----------------
__global__ __launch_bounds__(256) void k_gemm(const unsigned short* __restrict__ A, int lda,
                                              const unsigned short* __restrict__ BT, int ldb,
                                              int M, int K,
                                              const float* __restrict__ bias,
                                              float* __restrict__ outf) {
  __shared__ unsigned short sA[128 * 64];
  __shared__ unsigned short sB[128 * 64];
  int t = threadIdx.x;
  int bm = blockIdx.x;
  int lane = t & 63, wv = t >> 6;
  int wm = wv >> 1, wn = wv & 1;
  int l15 = lane & 15, lk = lane >> 4;

  f32x4 acc[4][4];
  #pragma unroll
  for (int mi = 0; mi < 4; mi++)
    #pragma unroll
    for (int ni = 0; ni < 4; ni++)
      acc[mi][ni] = (f32x4){0.f, 0.f, 0.f, 0.f};

  int nkt = K >> 6;
  for (int kt = 0; kt < nkt; kt++) {
    #pragma unroll
    for (int i = 0; i < 4; i++) {
      int f = i * 256 + t;
      int row = f >> 3, cl = f & 7;
      int cg = cl ^ (row & 7);
      int rg = bm * 128 + row;
      if (rg >= M) rg = M - 1;
      GLDS16(A + (size_t)rg * lda + kt * 64 + cg * 8, &sA[f * 8]);
    }
    #pragma unroll
    for (int i = 0; i < 4; i++) {
      int f = i * 256 + t;
      int row = f >> 3, cl = f & 7;
      int cg = cl ^ (row & 7);
      GLDS16(BT + (size_t)row * ldb + kt * 64 + cg * 8, &sB[f * 8]);
    }
    __syncthreads();

    short8 af[4][2], bf[4][2];
    #pragma unroll
    for (int mi = 0; mi < 4; mi++) {
      #pragma unroll
      for (int kk = 0; kk < 2; kk++) {
        int r = wm * 64 + mi * 16 + l15;
        int c = kk * 4 + lk;
        af[mi][kk] = *(const short8*)&sA[((r << 3) + (c ^ (r & 7))) << 3];
        int rb = wn * 64 + mi * 16 + l15;
        bf[mi][kk] = *(const short8*)&sB[((rb << 3) + (c ^ (rb & 7))) << 3];
      }
    }
    #pragma unroll
    for (int mi = 0; mi < 4; mi++)
      #pragma unroll
      for (int ni = 0; ni < 4; ni++)
        #pragma unroll
        for (int kk = 0; kk < 2; kk++)
          acc[mi][ni] = __builtin_amdgcn_mfma_f32_16x16x32_bf16(af[mi][kk], bf[ni][kk], acc[mi][ni], 0, 0, 0);
    __syncthreads();
  }

  #pragma unroll
  for (int mi = 0; mi < 4; mi++) {
    #pragma unroll
    for (int ni = 0; ni < 4; ni++) {
      int cg = wn * 64 + ni * 16 + l15;
      float bv = bias[cg];
      #pragma unroll
      for (int j = 0; j < 4; j++) {
        int rg = bm * 128 + wm * 64 + mi * 16 + lk * 4 + j;
        if (rg < M) outf[(size_t)rg * 128 + cg] = acc[mi][ni][j] + bv;
      }
    }
  }
}

// ---------------- launch ----------------
extern "C" void kernel_launch(void* const* d_in, const int* in_sizes, int n_in,
                              void* d_out, int out_size, void* d_ws, size_t ws_size,
                              hipStream_t stream) {
  const float* node_feat = (const float*)d_in[0];
  const int*   ei        = (const int*)d_in[1];
  const int*   et        = (const int*)d_in[2];
  const float* rel_w     = (const float*)d_in[3];
  const float* root_w    = (const float*)d_in[4];
  const float* bias      = (const float*)d_in[5];
  const float* proj_w    = (const float*)d_in[6];
  const float* proj_b    = (const float*)d_in[7];
  float* out = (float*)d_out;

  char* ws = (char*)d_ws;
  size_t off = 0;
  auto carve = [&](size_t bytes) { void* p = ws + off; off = (off + bytes + 255) & ~(size_t)255; return p; };
  unsigned short* Y    = (unsigned short*)carve((size_t)NN * KY * 2);      // 115.2 MB
  unsigned short* Hb   = (unsigned short*)carve((size_t)NN * 256 * 2);     // 25.6 MB [h1|h2] bf16
  unsigned short* xb   = (unsigned short*)carve((size_t)NN * DD * 2);      // 12.8 MB
  unsigned short* WT2  = (unsigned short*)carve((size_t)2 * KY * DD * 2);  // 0.59 MB
  unsigned short* PT   = (unsigned short*)carve((size_t)DD * 256 * 2);     // 64 KB
  int* cnt_vr          = (int*)carve((size_t)N2 * 4);
  int* rp2             = (int*)carve((size_t)(N2 + 1) * 4);
  int* cur2            = (int*)carve((size_t)N2 * 4);
  unsigned* packed     = (unsigned*)carve((size_t)NE * 4);                 // 2.4 MB
  int* bsum            = (int*)carve((size_t)512 * 4);
  int* boff            = (int*)carve((size_t)512 * 4);
  (void)ws_size; (void)in_sizes; (void)n_in; (void)out_size;

  hipMemsetAsync(cnt_vr, 0, (size_t)N2 * 4, stream);

  int egrid = (NE + 255) / 256;
  k_hist<<<egrid, 256, 0, stream>>>(ei, et, cnt_vr);
  k_scan1<<<NBS2, 256, 0, stream>>>(cnt_vr, bsum);
  k_scan2<<<1, 512, 0, stream>>>(bsum, boff);
  k_scan3<<<NBS2, 256, 0, stream>>>(cnt_vr, boff, rp2, cur2);
  k_scatter<<<egrid, 256, 0, stream>>>(ei, et, cur2, packed);

  k_xb<<<(NN * (DD / 2) + 255) / 256, 256, 0, stream>>>(node_feat, (unsigned*)xb);
  k_wt2<<<(2 * KY * DD + 255) / 256, 256, 0, stream>>>(rel_w, root_w, WT2);
  k_pt<<<(DD * 256 + 255) / 256, 256, 0, stream>>>(proj_w, PT);

  // layer 1: Y = xb @ W'(l=0); out_h1 = gather(Y) (+root,+bias,relu)
  k_ygemm<<<MGRID * 9, 256, 0, stream>>>(xb, DD, WT2, Y);
  k_aggD<<<NN / 4, 256, 0, stream>>>(Y, packed, rp2, bias,
                                     out + (size_t)NN * DD, Hb, 0);
  // layer 2: Y = h1 @ W'(l=1); out_h2 = gather(Y)
  k_ygemm<<<MGRID * 9, 256, 0, stream>>>(Hb, 256, WT2 + (size_t)KY * DD, Y);
  k_aggD<<<NN / 4, 256, 0, stream>>>(Y, packed, rp2, bias + DD,
                                     out + (size_t)2 * NN * DD, Hb, DD);
  // projection: final = [h1|h2] @ proj_w + proj_b
  k_gemm<<<MGRID, 256, 0, stream>>>(Hb, 256, PT, 256, NN, 256, proj_b, out);
}

// Round 8
// 279.101 us; speedup vs baseline: 1.2133x; 1.2133x over previous
//
#include <hip/hip_runtime.h>
#include <hip/hip_bf16.h>

#define NN 50000
#define NE 600000
#define DD 128
#define RR 8
#define KY 1152   /* Y cols: 8 relations * 128 + root 128 */

#define N2 (NN * RR)                       /* (v,r) segments, v-major */
#define SCHUNK 1024
#define NBS2 ((N2 + SCHUNK - 1) / SCHUNK)  /* 391 */
#define MGRID ((NN + 127) / 128)           /* 391 row-tiles */

typedef __attribute__((ext_vector_type(8))) short short8;
typedef __attribute__((ext_vector_type(4))) float f32x4;
typedef __attribute__((ext_vector_type(4))) unsigned uint4v;

__device__ __forceinline__ unsigned short f2b(float x){
  __hip_bfloat16 h = __float2bfloat16(x);
  return __builtin_bit_cast(unsigned short, h);
}
__device__ __forceinline__ float blo(unsigned u){ return __builtin_bit_cast(float, u << 16); }
__device__ __forceinline__ float bhi(unsigned u){ return __builtin_bit_cast(float, u & 0xFFFF0000u); }
__device__ __forceinline__ unsigned pack2(float a, float b){
  return (unsigned)f2b(a) | ((unsigned)f2b(b) << 16);
}

#define GLDS16(g, l) __builtin_amdgcn_global_load_lds( \
    (const __attribute__((address_space(1))) void*)(g), \
    (__attribute__((address_space(3))) void*)(l), 16, 0, 0)

// ---------------- edge structure build: CSR over v-major (dst, rel) segments ----------------
__global__ __launch_bounds__(256) void k_hist(const int* __restrict__ ei,
                                              const int* __restrict__ et,
                                              int* __restrict__ cnt) {
  int e = blockIdx.x * 256 + threadIdx.x;
  if (e < NE) {
    int dst = ei[NE + e];
    int r = et[e];
    atomicAdd(&cnt[dst * RR + r], 1);
  }
}

__global__ __launch_bounds__(256) void k_scan1(const int* __restrict__ cnt,
                                               int* __restrict__ bsum) {
  int b = blockIdx.x, t = threadIdx.x;
  int base = b * SCHUNK + t * 4;
  int s = 0;
  if (base < N2) {
    int4 v = *(const int4*)&cnt[base];
    s = v.x + v.y + v.z + v.w;
  }
  #pragma unroll
  for (int off = 32; off; off >>= 1) s += __shfl_down(s, off);
  __shared__ int wsum[4];
  int lane = t & 63, wv = t >> 6;
  if (lane == 0) wsum[wv] = s;
  __syncthreads();
  if (t == 0) bsum[b] = wsum[0] + wsum[1] + wsum[2] + wsum[3];
}

__global__ __launch_bounds__(512) void k_scan2(const int* __restrict__ bsum,
                                               int* __restrict__ boff) {
  int t = threadIdx.x, lane = t & 63, wv = t >> 6;
  int v = (t < NBS2) ? bsum[t] : 0;
  int x = v;
  #pragma unroll
  for (int off = 1; off < 64; off <<= 1) {
    int y = __shfl_up(x, off);
    if (lane >= off) x += y;
  }
  __shared__ int wt[8];
  if (lane == 63) wt[wv] = x;
  __syncthreads();
  int woff = 0;
  for (int w = 0; w < wv; w++) woff += wt[w];
  if (t < NBS2) boff[t] = woff + x - v;
}

__global__ __launch_bounds__(256) void k_scan3(const int* __restrict__ cnt,
                                               const int* __restrict__ boff,
                                               int* __restrict__ rp2,
                                               int* __restrict__ cur2) {
  int b = blockIdx.x, t = threadIdx.x;
  int lane = t & 63, wv = t >> 6;
  int base = b * SCHUNK + t * 4;
  int v[4] = {0, 0, 0, 0};
  int s = 0;
  if (base < N2) {
    int4 q = *(const int4*)&cnt[base];
    v[0] = q.x; v[1] = q.y; v[2] = q.z; v[3] = q.w;
    s = q.x + q.y + q.z + q.w;
  }
  int x = s;
  #pragma unroll
  for (int off = 1; off < 64; off <<= 1) {
    int y = __shfl_up(x, off);
    if (lane >= off) x += y;
  }
  __shared__ int wtot[4];
  if (lane == 63) wtot[wv] = x;
  __syncthreads();
  int woff = 0;
  for (int w = 0; w < wv; w++) woff += wtot[w];
  int exc = boff[b] + woff + x - s;
  if (base < N2) {
    #pragma unroll
    for (int j = 0; j < 4; j++) {
      cur2[base + j] = exc;
      rp2[base + j + 1] = exc + v[j];
      exc += v[j];
    }
  }
  if (b == 0 && t == 0) rp2[0] = 0;
}

__global__ __launch_bounds__(256) void k_scatter(const int* __restrict__ ei,
                                                 const int* __restrict__ et,
                                                 int* __restrict__ cur2,
                                                 unsigned* __restrict__ packed) {
  int e = blockIdx.x * 256 + threadIdx.x;
  if (e < NE) {
    int src = ei[e];
    int dst = ei[NE + e];
    int r = et[e];
    int p = atomicAdd(&cur2[dst * RR + r], 1);
    packed[p] = (unsigned)src | ((unsigned)r << 16);   // src < 65536
  }
}

// ---------------- prep: bf16 conversions ----------------
__global__ __launch_bounds__(256) void k_xb(const float* __restrict__ x,
                                            unsigned* __restrict__ xb2) {
  int i = blockIdx.x * 256 + threadIdx.x;
  if (i < NN * (DD / 2)) {
    float2 v = ((const float2*)x)[i];
    xb2[i] = pack2(v.x, v.y);
  }
}

// WT2[l][j][k] bf16, j in [0,1152): j<1024 -> rel_w[l][j>>7][k][j&127], else root_w[l][k][j-1024]
__global__ __launch_bounds__(256) void k_wt2(const float* __restrict__ rel_w,
                                             const float* __restrict__ root_w,
                                             unsigned short* __restrict__ WT2) {
  int idx = blockIdx.x * 256 + threadIdx.x;
  if (idx >= 2 * KY * DD) return;
  int k = idx % DD;
  int j = (idx / DD) % KY;
  int l = idx / (DD * KY);
  float v;
  if (j < RR * DD) v = rel_w[(((size_t)l * RR + (j >> 7)) * DD + k) * DD + (j & 127)];
  else             v = root_w[((size_t)l * DD + k) * DD + (j - RR * DD)];
  WT2[idx] = f2b(v);
}

// PT[n][k] = proj_w[k][n], k<256
__global__ __launch_bounds__(256) void k_pt(const float* __restrict__ proj_w,
                                            unsigned short* __restrict__ PT) {
  int idx = blockIdx.x * 256 + threadIdx.x;
  if (idx >= DD * 256) return;
  int k = idx % 256;
  int n = idx / 256;
  PT[idx] = f2b(proj_w[(size_t)k * DD + n]);
}

// ---------------- Y-GEMM v4: Y[M,1152] = A[M,128] @ W'[128,1152]  (bf16 out) ----------------
// One 128x128 tile per block, 8 waves (each 64x32 sub-tile). LDS-staged A+B
// (global_load_lds), XCD-grouped rt-major mapping so the 9 col-tiles of a
// row-tile run on one XCD (A fetched from HBM once -> L2 hits). C restaged
// into smA (free after last MFMA), 512 threads store 64B each.
__global__ __launch_bounds__(512) void k_ygemm(const unsigned short* __restrict__ A, int lda,
                                               const unsigned short* __restrict__ B2, /* [1152][128] */
                                               unsigned short* __restrict__ Y) {
  __shared__ unsigned short smA[128 * 128];   // 32 KB
  __shared__ unsigned short smB[128 * 128];   // 32 KB
  int t = threadIdx.x;
  // bijective XCD-grouped mapping (grid = MGRID*9 = 3519)
  const int nb = MGRID * 9, q8 = nb >> 3, r8 = nb & 7;   // 3519, 439, 7
  int xcd = blockIdx.x & 7, idx = blockIdx.x >> 3;
  int w = (xcd < r8 ? xcd * (q8 + 1) : r8 * (q8 + 1) + (xcd - r8) * q8) + idx;
  int rt = w / 9, ct = w % 9;

  int lane = t & 63, wv = t >> 6;             // wv 0..7
  int wm = wv >> 2, wn = wv & 3;              // 2M x 4N wave grid, 64x32 each
  int l15 = lane & 15, lk = lane >> 4;

  // stage A tile [128 rows][128 k] and B tile [128 outcols][128 k], swizzled src
  #pragma unroll
  for (int i = 0; i < 4; i++) {
    int f = i * 512 + t;
    int row = f >> 4, cl = f & 15;
    int cg = cl ^ (row & 15);
    int rg = rt * 128 + row; if (rg >= NN) rg = NN - 1;
    GLDS16(A + (size_t)rg * lda + cg * 8, &smA[f * 8]);
  }
  #pragma unroll
  for (int i = 0; i < 4; i++) {
    int f = i * 512 + t;
    int row = f >> 4, cl = f & 15;
    int cg = cl ^ (row & 15);
    GLDS16(B2 + (size_t)(ct * 128 + row) * DD + cg * 8, &smB[f * 8]);
  }
  __syncthreads();

  f32x4 acc[4][2];
  #pragma unroll
  for (int mi = 0; mi < 4; mi++)
    #pragma unroll
    for (int ni = 0; ni < 2; ni++)
      acc[mi][ni] = (f32x4){0.f, 0.f, 0.f, 0.f};

  #pragma unroll
  for (int kk = 0; kk < 4; kk++) {
    short8 af[4], bf[2];
    int c = kk * 4 + lk;
    #pragma unroll
    for (int q = 0; q < 4; q++) {
      int r = wm * 64 + q * 16 + l15;
      af[q] = *(const short8*)&smA[r * 128 + ((c ^ (r & 15)) << 3)];
    }
    #pragma unroll
    for (int q = 0; q < 2; q++) {
      int rb = wn * 32 + q * 16 + l15;
      bf[q] = *(const short8*)&smB[rb * 128 + ((c ^ (rb & 15)) << 3)];
    }
    #pragma unroll
    for (int mi = 0; mi < 4; mi++)
      #pragma unroll
      for (int ni = 0; ni < 2; ni++)
        acc[mi][ni] = __builtin_amdgcn_mfma_f32_16x16x32_bf16(af[mi], bf[ni], acc[mi][ni], 0, 0, 0);
  }
  __syncthreads();   // all MFMA reads of smA/smB done

  // restage C into smA, bf16, chunk-swizzled: col c of row r -> chunk (c>>3)^(r&7)
  #pragma unroll
  for (int mi = 0; mi < 4; mi++)
    #pragma unroll
    for (int ni = 0; ni < 2; ni++) {
      int col = wn * 32 + ni * 16 + l15;
      #pragma unroll
      for (int j = 0; j < 4; j++) {
        int row = wm * 64 + mi * 16 + lk * 4 + j;
        smA[row * 128 + ((((col >> 3) ^ (row & 7)) << 3) | (col & 7))] = f2b(acc[mi][ni][j]);
      }
    }
  __syncthreads();

  // write-out: thread t covers quarter-row (32 shorts = 64B) via 4x16B chunks
  {
    int row = t >> 2, q4 = t & 3;
    int rg = rt * 128 + row;
    if (rg < NN) {
      unsigned short* dst = Y + (size_t)rg * KY + ct * 128 + q4 * 32;
      #pragma unroll
      for (int i = 0; i < 4; i++) {
        int cc = q4 * 4 + i;
        ((uint4v*)dst)[i] = *(const uint4v*)&smA[row * 128 + ((cc ^ (row & 7)) << 3)];
      }
    }
  }
}

// ---------------- weighted gather: out[v] = sum_e w_e * Y[src_e, r_e*128:] + Y[v,1024:] + bias ----------------
__global__ __launch_bounds__(256) void k_aggD(const unsigned short* __restrict__ Y,
                                              const unsigned* __restrict__ packed,
                                              const int* __restrict__ rp2,
                                              const float* __restrict__ bias,
                                              float* __restrict__ outf,
                                              unsigned short* __restrict__ hb, int hboff) {
  int v = blockIdx.x * 4 + (threadIdx.x >> 6);
  int lane = threadIdx.x & 63;
  int q = lane >> 4, sub = lane & 15;

  // fenceposts rp2[v*8 .. v*8+8] on lanes 0..8
  int f = 0;
  if (lane <= 8) f = rp2[v * RR + lane];
  int fn = __shfl(f, lane + 1);             // lane l: rp2[v*8+l+1] (l<8 valid)
  int c = fn - f;
  float winv = (lane < 8 && c > 0) ? 1.f / (float)c : 0.f;
  int e0 = __shfl(f, 0), e1 = __shfl(f, 8);

  float acc[8];
  #pragma unroll
  for (int j = 0; j < 8; j++) acc[j] = 0.f;

  // 4 quarter-waves, each owns 16B of the row, 4 edges in flight
  for (int e = e0 + q; e < e1; e += 4) {
    unsigned rec = packed[e];
    int src = rec & 0xFFFF;
    int r = rec >> 16;
    float w = __shfl(winv, r);
    const uint4v* p = (const uint4v*)(Y + (size_t)src * KY + r * DD + sub * 8);
    uint4v u = *p;
    #pragma unroll
    for (int i = 0; i < 4; i++) {
      acc[2 * i]     += w * blo(u[i]);
      acc[2 * i + 1] += w * bhi(u[i]);
    }
  }

  // root term (once, quarter 0)
  if (q == 0) {
    uint4v u = *(const uint4v*)(Y + (size_t)v * KY + RR * DD + sub * 8);
    #pragma unroll
    for (int i = 0; i < 4; i++) {
      acc[2 * i]     += blo(u[i]);
      acc[2 * i + 1] += bhi(u[i]);
    }
  }

  // reduce across quarters
  #pragma unroll
  for (int j = 0; j < 8; j++) {
    acc[j] += __shfl_xor(acc[j], 32);
    acc[j] += __shfl_xor(acc[j], 16);
  }

  if (q == 0) {
    float4 b0 = *(const float4*)&bias[sub * 8];
    float4 b1 = *(const float4*)&bias[sub * 8 + 4];
    float val[8];
    val[0] = fmaxf(acc[0] + b0.x, 0.f); val[1] = fmaxf(acc[1] + b0.y, 0.f);
    val[2] = fmaxf(acc[2] + b0.z, 0.f); val[3] = fmaxf(acc[3] + b0.w, 0.f);
    val[4] = fmaxf(acc[4] + b1.x, 0.f); val[5] = fmaxf(acc[5] + b1.y, 0.f);
    val[6] = fmaxf(acc[6] + b1.z, 0.f); val[7] = fmaxf(acc[7] + b1.w, 0.f);
    float4* of = (float4*)&outf[(size_t)v * DD + sub * 8];
    of[0] = (float4){val[0], val[1], val[2], val[3]};
    of[1] = (float4){val[4], val[5], val[6], val[7]};
    uint4v hv;
    #pragma unroll
    for (int i = 0; i < 4; i++) hv[i] = pack2(val[2 * i], val[2 * i + 1]);
    *(uint4v*)(hb + (size_t)v * 256 + hboff + sub * 8) = hv;
  }
}

// ---------------- bf16 MFMA GEMM (projection): C[M,128] = A[M,K] * BT[128,K]^T + bias ----------------
__global__ __launch_bounds__(256) void k_gemm(const unsigned short* __restrict__ A, int lda,
                                              const unsigned short* __restrict__ BT, int ldb,
                                              int M, int K,
                                              const float* __restrict__ bias,
                                              float* __restrict__ outf) {
  __shared__ unsigned short sA[128 * 64];
  __shared__ unsigned short sB[128 * 64];
  int t = threadIdx.x;
  int bm = blockIdx.x;
  int lane = t & 63, wv = t >> 6;
  int wm = wv >> 1, wn = wv & 1;
  int l15 = lane & 15, lk = lane >> 4;

  f32x4 acc[4][4];
  #pragma unroll
  for (int mi = 0; mi < 4; mi++)
    #pragma unroll
    for (int ni = 0; ni < 4; ni++)
      acc[mi][ni] = (f32x4){0.f, 0.f, 0.f, 0.f};

  int nkt = K >> 6;
  for (int kt = 0; kt < nkt; kt++) {
    #pragma unroll
    for (int i = 0; i < 4; i++) {
      int f = i * 256 + t;
      int row = f >> 3, cl = f & 7;
      int cg = cl ^ (row & 7);
      int rg = bm * 128 + row;
      if (rg >= M) rg = M - 1;
      GLDS16(A + (size_t)rg * lda + kt * 64 + cg * 8, &sA[f * 8]);
    }
    #pragma unroll
    for (int i = 0; i < 4; i++) {
      int f = i * 256 + t;
      int row = f >> 3, cl = f & 7;
      int cg = cl ^ (row & 7);
      GLDS16(BT + (size_t)row * ldb + kt * 64 + cg * 8, &sB[f * 8]);
    }
    __syncthreads();

    short8 af[4][2], bf[4][2];
    #pragma unroll
    for (int mi = 0; mi < 4; mi++) {
      #pragma unroll
      for (int kk = 0; kk < 2; kk++) {
        int r = wm * 64 + mi * 16 + l15;
        int c = kk * 4 + lk;
        af[mi][kk] = *(const short8*)&sA[((r << 3) + (c ^ (r & 7))) << 3];
        int rb = wn * 64 + mi * 16 + l15;
        bf[mi][kk] = *(const short8*)&sB[((rb << 3) + (c ^ (rb & 7))) << 3];
      }
    }
    #pragma unroll
    for (int mi = 0; mi < 4; mi++)
      #pragma unroll
      for (int ni = 0; ni < 4; ni++)
        #pragma unroll
        for (int kk = 0; kk < 2; kk++)
          acc[mi][ni] = __builtin_amdgcn_mfma_f32_16x16x32_bf16(af[mi][kk], bf[ni][kk], acc[mi][ni], 0, 0, 0);
    __syncthreads();
  }

  #pragma unroll
  for (int mi = 0; mi < 4; mi++) {
    #pragma unroll
    for (int ni = 0; ni < 4; ni++) {
      int cg = wn * 64 + ni * 16 + l15;
      float bv = bias[cg];
      #pragma unroll
      for (int j = 0; j < 4; j++) {
        int rg = bm * 128 + wm * 64 + mi * 16 + lk * 4 + j;
        if (rg < M) outf[(size_t)rg * 128 + cg] = acc[mi][ni][j] + bv;
      }
    }
  }
}

// ---------------- launch ----------------
extern "C" void kernel_launch(void* const* d_in, const int* in_sizes, int n_in,
                              void* d_out, int out_size, void* d_ws, size_t ws_size,
                              hipStream_t stream) {
  const float* node_feat = (const float*)d_in[0];
  const int*   ei        = (const int*)d_in[1];
  const int*   et        = (const int*)d_in[2];
  const float* rel_w     = (const float*)d_in[3];
  const float* root_w    = (const float*)d_in[4];
  const float* bias      = (const float*)d_in[5];
  const float* proj_w    = (const float*)d_in[6];
  const float* proj_b    = (const float*)d_in[7];
  float* out = (float*)d_out;

  char* ws = (char*)d_ws;
  size_t off = 0;
  auto carve = [&](size_t bytes) { void* p = ws + off; off = (off + bytes + 255) & ~(size_t)255; return p; };
  unsigned short* Y    = (unsigned short*)carve((size_t)NN * KY * 2);      // 115.2 MB
  unsigned short* Hb   = (unsigned short*)carve((size_t)NN * 256 * 2);     // 25.6 MB [h1|h2] bf16
  unsigned short* xb   = (unsigned short*)carve((size_t)NN * DD * 2);      // 12.8 MB
  unsigned short* WT2  = (unsigned short*)carve((size_t)2 * KY * DD * 2);  // 0.59 MB
  unsigned short* PT   = (unsigned short*)carve((size_t)DD * 256 * 2);     // 64 KB
  int* cnt_vr          = (int*)carve((size_t)N2 * 4);
  int* rp2             = (int*)carve((size_t)(N2 + 1) * 4);
  int* cur2            = (int*)carve((size_t)N2 * 4);
  unsigned* packed     = (unsigned*)carve((size_t)NE * 4);                 // 2.4 MB
  int* bsum            = (int*)carve((size_t)512 * 4);
  int* boff            = (int*)carve((size_t)512 * 4);
  (void)ws_size; (void)in_sizes; (void)n_in; (void)out_size;

  hipMemsetAsync(cnt_vr, 0, (size_t)N2 * 4, stream);

  int egrid = (NE + 255) / 256;
  k_hist<<<egrid, 256, 0, stream>>>(ei, et, cnt_vr);
  k_scan1<<<NBS2, 256, 0, stream>>>(cnt_vr, bsum);
  k_scan2<<<1, 512, 0, stream>>>(bsum, boff);
  k_scan3<<<NBS2, 256, 0, stream>>>(cnt_vr, boff, rp2, cur2);
  k_scatter<<<egrid, 256, 0, stream>>>(ei, et, cur2, packed);

  k_xb<<<(NN * (DD / 2) + 255) / 256, 256, 0, stream>>>(node_feat, (unsigned*)xb);
  k_wt2<<<(2 * KY * DD + 255) / 256, 256, 0, stream>>>(rel_w, root_w, WT2);
  k_pt<<<(DD * 256 + 255) / 256, 256, 0, stream>>>(proj_w, PT);

  // layer 1: Y = xb @ W'(l=0); out_h1 = gather(Y) (+root,+bias,relu)
  k_ygemm<<<MGRID * 9, 512, 0, stream>>>(xb, DD, WT2, Y);
  k_aggD<<<NN / 4, 256, 0, stream>>>(Y, packed, rp2, bias,
                                     out + (size_t)NN * DD, Hb, 0);
  // layer 2: Y = h1 @ W'(l=1); out_h2 = gather(Y)
  k_ygemm<<<MGRID * 9, 512, 0, stream>>>(Hb, 256, WT2 + (size_t)KY * DD, Y);
  k_aggD<<<NN / 4, 256, 0, stream>>>(Y, packed, rp2, bias + DD,
                                     out + (size_t)2 * NN * DD, Hb, DD);
  // projection: final = [h1|h2] @ proj_w + proj_b
  k_gemm<<<MGRID, 256, 0, stream>>>(Hb, 256, PT, 256, NN, 256, proj_b, out);
}

// Round 10
// 262.441 us; speedup vs baseline: 1.2904x; 1.0635x over previous
//
#include <hip/hip_runtime.h>
#include <hip/hip_bf16.h>

#define NN 50000
#define NE 600000
#define DD 128
#define RR 8
#define KY 1152   /* Y cols: 8 relations * 128 + root 128 */

#define N2 (NN * RR)                       /* (v,r) segments, v-major */
#define SCHUNK 1024
#define NBS2 ((N2 + SCHUNK - 1) / SCHUNK)  /* 391 */
#define MGRID ((NN + 127) / 128)           /* 391 row-tiles */

typedef __attribute__((ext_vector_type(8))) short short8;
typedef __attribute__((ext_vector_type(4))) float f32x4;
typedef __attribute__((ext_vector_type(4))) unsigned uint4v;

__device__ __forceinline__ unsigned short f2b(float x){
  __hip_bfloat16 h = __float2bfloat16(x);
  return __builtin_bit_cast(unsigned short, h);
}
__device__ __forceinline__ float blo(unsigned u){ return __builtin_bit_cast(float, u << 16); }
__device__ __forceinline__ float bhi(unsigned u){ return __builtin_bit_cast(float, u & 0xFFFF0000u); }
__device__ __forceinline__ unsigned pack2(float a, float b){
  return (unsigned)f2b(a) | ((unsigned)f2b(b) << 16);
}

#define GLDS16(g, l) __builtin_amdgcn_global_load_lds( \
    (const __attribute__((address_space(1))) void*)(g), \
    (__attribute__((address_space(3))) void*)(l), 16, 0, 0)

// ---------------- edge structure build: CSR over v-major (dst, rel) segments ----------------
__global__ __launch_bounds__(256) void k_hist(const int* __restrict__ ei,
                                              const int* __restrict__ et,
                                              int* __restrict__ cnt) {
  int e = blockIdx.x * 256 + threadIdx.x;
  if (e < NE) {
    int dst = ei[NE + e];
    int r = et[e];
    atomicAdd(&cnt[dst * RR + r], 1);
  }
}

__global__ __launch_bounds__(256) void k_scan1(const int* __restrict__ cnt,
                                               int* __restrict__ bsum) {
  int b = blockIdx.x, t = threadIdx.x;
  int base = b * SCHUNK + t * 4;
  int s = 0;
  if (base < N2) {
    int4 v = *(const int4*)&cnt[base];
    s = v.x + v.y + v.z + v.w;
  }
  #pragma unroll
  for (int off = 32; off; off >>= 1) s += __shfl_down(s, off);
  __shared__ int wsum[4];
  int lane = t & 63, wv = t >> 6;
  if (lane == 0) wsum[wv] = s;
  __syncthreads();
  if (t == 0) bsum[b] = wsum[0] + wsum[1] + wsum[2] + wsum[3];
}

__global__ __launch_bounds__(512) void k_scan2(const int* __restrict__ bsum,
                                               int* __restrict__ boff) {
  int t = threadIdx.x, lane = t & 63, wv = t >> 6;
  int v = (t < NBS2) ? bsum[t] : 0;
  int x = v;
  #pragma unroll
  for (int off = 1; off < 64; off <<= 1) {
    int y = __shfl_up(x, off);
    if (lane >= off) x += y;
  }
  __shared__ int wt[8];
  if (lane == 63) wt[wv] = x;
  __syncthreads();
  int woff = 0;
  for (int w = 0; w < wv; w++) woff += wt[w];
  if (t < NBS2) boff[t] = woff + x - v;
}

__global__ __launch_bounds__(256) void k_scan3(const int* __restrict__ cnt,
                                               const int* __restrict__ boff,
                                               int* __restrict__ rp2,
                                               int* __restrict__ cur2) {
  int b = blockIdx.x, t = threadIdx.x;
  int lane = t & 63, wv = t >> 6;
  int base = b * SCHUNK + t * 4;
  int v[4] = {0, 0, 0, 0};
  int s = 0;
  if (base < N2) {
    int4 q = *(const int4*)&cnt[base];
    v[0] = q.x; v[1] = q.y; v[2] = q.z; v[3] = q.w;
    s = q.x + q.y + q.z + q.w;
  }
  int x = s;
  #pragma unroll
  for (int off = 1; off < 64; off <<= 1) {
    int y = __shfl_up(x, off);
    if (lane >= off) x += y;
  }
  __shared__ int wtot[4];
  if (lane == 63) wtot[wv] = x;
  __syncthreads();
  int woff = 0;
  for (int w = 0; w < wv; w++) woff += wtot[w];
  int exc = boff[b] + woff + x - s;
  if (base < N2) {
    #pragma unroll
    for (int j = 0; j < 4; j++) {
      cur2[base + j] = exc;
      rp2[base + j + 1] = exc + v[j];
      exc += v[j];
    }
  }
  if (b == 0 && t == 0) rp2[0] = 0;
}

__global__ __launch_bounds__(256) void k_scatter(const int* __restrict__ ei,
                                                 const int* __restrict__ et,
                                                 int* __restrict__ cur2,
                                                 unsigned* __restrict__ packed) {
  int e = blockIdx.x * 256 + threadIdx.x;
  if (e < NE) {
    int src = ei[e];
    int dst = ei[NE + e];
    int r = et[e];
    int p = atomicAdd(&cur2[dst * RR + r], 1);
    packed[p] = (unsigned)src | ((unsigned)r << 16);   // src < 65536
  }
}

// ---------------- prep: bf16 conversions ----------------
__global__ __launch_bounds__(256) void k_xb(const float* __restrict__ x,
                                            unsigned* __restrict__ xb2) {
  int i = blockIdx.x * 256 + threadIdx.x;
  if (i < NN * (DD / 2)) {
    float2 v = ((const float2*)x)[i];
    xb2[i] = pack2(v.x, v.y);
  }
}

// WT2[l][j][k] bf16, j in [0,1152): j<1024 -> rel_w[l][j>>7][k][j&127], else root_w[l][k][j-1024]
__global__ __launch_bounds__(256) void k_wt2(const float* __restrict__ rel_w,
                                             const float* __restrict__ root_w,
                                             unsigned short* __restrict__ WT2) {
  int idx = blockIdx.x * 256 + threadIdx.x;
  if (idx >= 2 * KY * DD) return;
  int k = idx % DD;
  int j = (idx / DD) % KY;
  int l = idx / (DD * KY);
  float v;
  if (j < RR * DD) v = rel_w[(((size_t)l * RR + (j >> 7)) * DD + k) * DD + (j & 127)];
  else             v = root_w[((size_t)l * DD + k) * DD + (j - RR * DD)];
  WT2[idx] = f2b(v);
}

// PT[n][k] = proj_w[k][n], k<256
__global__ __launch_bounds__(256) void k_pt(const float* __restrict__ proj_w,
                                            unsigned short* __restrict__ PT) {
  int idx = blockIdx.x * 256 + threadIdx.x;
  if (idx >= DD * 256) return;
  int k = idx % 256;
  int n = idx / 256;
  PT[idx] = f2b(proj_w[(size_t)k * DD + n]);
}

// ---------------- Y-GEMM v6: Y[M,1152] = A[M,128] @ W'[128,1152]  (bf16 out) ----------------
// One 128x128 tile per block, 8 waves (64x32 sub-tile each). ONLY A staged in
// LDS (32 KB); strictly m97-ordered: GLDS -> barrier -> (B reg loads + ds_read
// + MFMA). C stored directly as per-lane u16 (no restage, 1 barrier total).
// XCD-grouped rt-major map keeps a row-tile's 9 col-tiles on one XCD.
__global__ __launch_bounds__(512) void k_ygemm(const unsigned short* __restrict__ A, int lda,
                                               const unsigned short* __restrict__ B2, /* [1152][128] */
                                               unsigned short* __restrict__ Y) {
  __shared__ unsigned short smA[128 * 128];   // 32 KB
  int t = threadIdx.x;
  // bijective XCD-grouped mapping (grid = MGRID*9 = 3519)
  const int nb = MGRID * 9, q8 = nb >> 3, r8 = nb & 7;   // 3519, 439, 7
  int xcd = blockIdx.x & 7, idx = blockIdx.x >> 3;
  int w = (xcd < r8 ? xcd * (q8 + 1) : r8 * (q8 + 1) + (xcd - r8) * q8) + idx;
  int rt = w / 9, ct = w % 9;

  int lane = t & 63, wv = t >> 6;             // wv 0..7
  int wm = wv >> 2, wn = wv & 3;              // 2M x 4N wave grid, 64x32 each
  int l15 = lane & 15, lk = lane >> 4;

  // issue A-stage (swizzled source -> linear LDS); nothing else before barrier
  #pragma unroll
  for (int i = 0; i < 4; i++) {
    int f = i * 512 + t;
    int row = f >> 4, cl = f & 15;
    int cg = cl ^ (row & 15);
    int rg = rt * 128 + row; if (rg >= NN) rg = NN - 1;
    GLDS16(A + (size_t)rg * lda + cg * 8, &smA[f * 8]);
  }
  __syncthreads();   // A tile ready

  // B fragments direct from L2 (0.29 MB, hot on this XCD)
  short8 bf[4][2];
  #pragma unroll
  for (int kk = 0; kk < 4; kk++)
    #pragma unroll
    for (int q = 0; q < 2; q++) {
      int rb = ct * 128 + wn * 32 + q * 16 + l15;
      bf[kk][q] = *(const short8*)(B2 + (size_t)rb * DD + (kk * 4 + lk) * 8);
    }

  f32x4 acc[4][2];
  #pragma unroll
  for (int mi = 0; mi < 4; mi++)
    #pragma unroll
    for (int ni = 0; ni < 2; ni++)
      acc[mi][ni] = (f32x4){0.f, 0.f, 0.f, 0.f};

  #pragma unroll
  for (int kk = 0; kk < 4; kk++) {
    short8 af[4];
    int c = kk * 4 + lk;
    #pragma unroll
    for (int q = 0; q < 4; q++) {
      int r = wm * 64 + q * 16 + l15;
      af[q] = *(const short8*)&smA[r * 128 + ((c ^ (r & 15)) << 3)];
    }
    #pragma unroll
    for (int mi = 0; mi < 4; mi++)
      #pragma unroll
      for (int ni = 0; ni < 2; ni++)
        acc[mi][ni] = __builtin_amdgcn_mfma_f32_16x16x32_bf16(af[mi], bf[kk][ni], acc[mi][ni], 0, 0, 0);
  }

  // direct store: per-lane u16 (16-lane 32B segments; L2 merges lines)
  #pragma unroll
  for (int mi = 0; mi < 4; mi++) {
    #pragma unroll
    for (int ni = 0; ni < 2; ni++) {
      int col = ct * 128 + wn * 32 + ni * 16 + l15;
      #pragma unroll
      for (int j = 0; j < 4; j++) {
        int rg = rt * 128 + wm * 64 + mi * 16 + lk * 4 + j;
        if (rg < NN) Y[(size_t)rg * KY + col] = f2b(acc[mi][ni][j]);
      }
    }
  }
}

// ---------------- weighted gather: out[v] = sum_e w_e * Y[src_e, r_e*128:] + Y[v,1024:] + bias ----------------
__global__ __launch_bounds__(256) void k_aggD(const unsigned short* __restrict__ Y,
                                              const unsigned* __restrict__ packed,
                                              const int* __restrict__ rp2,
                                              const float* __restrict__ bias,
                                              float* __restrict__ outf,
                                              unsigned short* __restrict__ hb, int hboff) {
  int v = blockIdx.x * 4 + (threadIdx.x >> 6);
  int lane = threadIdx.x & 63;
  int q = lane >> 4, sub = lane & 15;

  // fenceposts rp2[v*8 .. v*8+8] on lanes 0..8
  int f = 0;
  if (lane <= 8) f = rp2[v * RR + lane];
  int fn = __shfl(f, lane + 1);             // lane l: rp2[v*8+l+1] (l<8 valid)
  int c = fn - f;
  float winv = (lane < 8 && c > 0) ? 1.f / (float)c : 0.f;
  int e0 = __shfl(f, 0), e1 = __shfl(f, 8);

  float acc[8];
  #pragma unroll
  for (int j = 0; j < 8; j++) acc[j] = 0.f;

  // 4 quarter-waves, each owns 16B of the row, 4 edges in flight
  for (int e = e0 + q; e < e1; e += 4) {
    unsigned rec = packed[e];
    int src = rec & 0xFFFF;
    int r = rec >> 16;
    float w = __shfl(winv, r);
    const uint4v* p = (const uint4v*)(Y + (size_t)src * KY + r * DD + sub * 8);
    uint4v u = *p;
    #pragma unroll
    for (int i = 0; i < 4; i++) {
      acc[2 * i]     += w * blo(u[i]);
      acc[2 * i + 1] += w * bhi(u[i]);
    }
  }

  // root term (once, quarter 0)
  if (q == 0) {
    uint4v u = *(const uint4v*)(Y + (size_t)v * KY + RR * DD + sub * 8);
    #pragma unroll
    for (int i = 0; i < 4; i++) {
      acc[2 * i]     += blo(u[i]);
      acc[2 * i + 1] += bhi(u[i]);
    }
  }

  // reduce across quarters
  #pragma unroll
  for (int j = 0; j < 8; j++) {
    acc[j] += __shfl_xor(acc[j], 32);
    acc[j] += __shfl_xor(acc[j], 16);
  }

  if (q == 0) {
    float4 b0 = *(const float4*)&bias[sub * 8];
    float4 b1 = *(const float4*)&bias[sub * 8 + 4];
    float val[8];
    val[0] = fmaxf(acc[0] + b0.x, 0.f); val[1] = fmaxf(acc[1] + b0.y, 0.f);
    val[2] = fmaxf(acc[2] + b0.z, 0.f); val[3] = fmaxf(acc[3] + b0.w, 0.f);
    val[4] = fmaxf(acc[4] + b1.x, 0.f); val[5] = fmaxf(acc[5] + b1.y, 0.f);
    val[6] = fmaxf(acc[6] + b1.z, 0.f); val[7] = fmaxf(acc[7] + b1.w, 0.f);
    float4* of = (float4*)&outf[(size_t)v * DD + sub * 8];
    of[0] = (float4){val[0], val[1], val[2], val[3]};
    of[1] = (float4){val[4], val[5], val[6], val[7]};
    uint4v hv;
    #pragma unroll
    for (int i = 0; i < 4; i++) hv[i] = pack2(val[2 * i], val[2 * i + 1]);
    *(uint4v*)(hb + (size_t)v * 256 + hboff + sub * 8) = hv;
  }
}

// ---------------- bf16 MFMA GEMM (projection): C[M,128] = A[M,K] * BT[128,K]^T + bias ----------------
__global__ __launch_bounds__(256) void k_gemm(const unsigned short* __restrict__ A, int lda,
                                              const unsigned short* __restrict__ BT, int ldb,
                                              int M, int K,
                                              const float* __restrict__ bias,
                                              float* __restrict__ outf) {
  __shared__ unsigned short sA[128 * 64];
  __shared__ unsigned short sB[128 * 64];
  int t = threadIdx.x;
  int bm = blockIdx.x;
  int lane = t & 63, wv = t >> 6;
  int wm = wv >> 1, wn = wv & 1;
  int l15 = lane & 15, lk = lane >> 4;

  f32x4 acc[4][4];
  #pragma unroll
  for (int mi = 0; mi < 4; mi++)
    #pragma unroll
    for (int ni = 0; ni < 4; ni++)
      acc[mi][ni] = (f32x4){0.f, 0.f, 0.f, 0.f};

  int nkt = K >> 6;
  for (int kt = 0; kt < nkt; kt++) {
    #pragma unroll
    for (int i = 0; i < 4; i++) {
      int f = i * 256 + t;
      int row = f >> 3, cl = f & 7;
      int cg = cl ^ (row & 7);
      int rg = bm * 128 + row;
      if (rg >= M) rg = M - 1;
      GLDS16(A + (size_t)rg * lda + kt * 64 + cg * 8, &sA[f * 8]);
    }
    #pragma unroll
    for (int i = 0; i < 4; i++) {
      int f = i * 256 + t;
      int row = f >> 3, cl = f & 7;
      int cg = cl ^ (row & 7);
      GLDS16(BT + (size_t)row * ldb + kt * 64 + cg * 8, &sB[f * 8]);
    }
    __syncthreads();

    short8 af[4][2], bf[4][2];
    #pragma unroll
    for (int mi = 0; mi < 4; mi++) {
      #pragma unroll
      for (int kk = 0; kk < 2; kk++) {
        int r = wm * 64 + mi * 16 + l15;
        int c = kk * 4 + lk;
        af[mi][kk] = *(const short8*)&sA[((r << 3) + (c ^ (r & 7))) << 3];
        int rb = wn * 64 + mi * 16 + l15;
        bf[mi][kk] = *(const short8*)&sB[((rb << 3) + (c ^ (rb & 7))) << 3];
      }
    }
    #pragma unroll
    for (int mi = 0; mi < 4; mi++)
      #pragma unroll
      for (int ni = 0; ni < 4; ni++)
        #pragma unroll
        for (int kk = 0; kk < 2; kk++)
          acc[mi][ni] = __builtin_amdgcn_mfma_f32_16x16x32_bf16(af[mi][kk], bf[ni][kk], acc[mi][ni], 0, 0, 0);
    __syncthreads();
  }

  #pragma unroll
  for (int mi = 0; mi < 4; mi++) {
    #pragma unroll
    for (int ni = 0; ni < 4; ni++) {
      int cg = wn * 64 + ni * 16 + l15;
      float bv = bias[cg];
      #pragma unroll
      for (int j = 0; j < 4; j++) {
        int rg = bm * 128 + wm * 64 + mi * 16 + lk * 4 + j;
        if (rg < M) outf[(size_t)rg * 128 + cg] = acc[mi][ni][j] + bv;
      }
    }
  }
}

// ---------------- launch ----------------
extern "C" void kernel_launch(void* const* d_in, const int* in_sizes, int n_in,
                              void* d_out, int out_size, void* d_ws, size_t ws_size,
                              hipStream_t stream) {
  const float* node_feat = (const float*)d_in[0];
  const int*   ei        = (const int*)d_in[1];
  const int*   et        = (const int*)d_in[2];
  const float* rel_w     = (const float*)d_in[3];
  const float* root_w    = (const float*)d_in[4];
  const float* bias      = (const float*)d_in[5];
  const float* proj_w    = (const float*)d_in[6];
  const float* proj_b    = (const float*)d_in[7];
  float* out = (float*)d_out;

  char* ws = (char*)d_ws;
  size_t off = 0;
  auto carve = [&](size_t bytes) { void* p = ws + off; off = (off + bytes + 255) & ~(size_t)255; return p; };
  unsigned short* Y    = (unsigned short*)carve((size_t)NN * KY * 2);      // 115.2 MB
  unsigned short* Hb   = (unsigned short*)carve((size_t)NN * 256 * 2);     // 25.6 MB [h1|h2] bf16
  unsigned short* xb   = (unsigned short*)carve((size_t)NN * DD * 2);      // 12.8 MB
  unsigned short* WT2  = (unsigned short*)carve((size_t)2 * KY * DD * 2);  // 0.59 MB
  unsigned short* PT   = (unsigned short*)carve((size_t)DD * 256 * 2);     // 64 KB
  int* cnt_vr          = (int*)carve((size_t)N2 * 4);
  int* rp2             = (int*)carve((size_t)(N2 + 1) * 4);
  int* cur2            = (int*)carve((size_t)N2 * 4);
  unsigned* packed     = (unsigned*)carve((size_t)NE * 4);                 // 2.4 MB
  int* bsum            = (int*)carve((size_t)512 * 4);
  int* boff            = (int*)carve((size_t)512 * 4);
  (void)ws_size; (void)in_sizes; (void)n_in; (void)out_size;

  hipMemsetAsync(cnt_vr, 0, (size_t)N2 * 4, stream);

  int egrid = (NE + 255) / 256;
  k_hist<<<egrid, 256, 0, stream>>>(ei, et, cnt_vr);
  k_scan1<<<NBS2, 256, 0, stream>>>(cnt_vr, bsum);
  k_scan2<<<1, 512, 0, stream>>>(bsum, boff);
  k_scan3<<<NBS2, 256, 0, stream>>>(cnt_vr, boff, rp2, cur2);
  k_scatter<<<egrid, 256, 0, stream>>>(ei, et, cur2, packed);

  k_xb<<<(NN * (DD / 2) + 255) / 256, 256, 0, stream>>>(node_feat, (unsigned*)xb);
  k_wt2<<<(2 * KY * DD + 255) / 256, 256, 0, stream>>>(rel_w, root_w, WT2);
  k_pt<<<(DD * 256 + 255) / 256, 256, 0, stream>>>(proj_w, PT);

  // layer 1: Y = xb @ W'(l=0); out_h1 = gather(Y) (+root,+bias,relu)
  k_ygemm<<<MGRID * 9, 512, 0, stream>>>(xb, DD, WT2, Y);
  k_aggD<<<NN / 4, 256, 0, stream>>>(Y, packed, rp2, bias,
                                     out + (size_t)NN * DD, Hb, 0);
  // layer 2: Y = h1 @ W'(l=1); out_h2 = gather(Y)
  k_ygemm<<<MGRID * 9, 512, 0, stream>>>(Hb, 256, WT2 + (size_t)KY * DD, Y);
  k_aggD<<<NN / 4, 256, 0, stream>>>(Y, packed, rp2, bias + DD,
                                     out + (size_t)2 * NN * DD, Hb, DD);
  // projection: final = [h1|h2] @ proj_w + proj_b
  k_gemm<<<MGRID, 256, 0, stream>>>(Hb, 256, PT, 256, NN, 256, proj_b, out);
}